// Round 5
// baseline (8113.422 us; speedup 1.0000x reference)
//
#include <hip/hip_runtime.h>

// ---------------------------------------------------------------------------
// 2-layer LSTM, T=1024, B=32, D=256, H=512. Inputs fp32, OUTPUT fp32.
//   pack_w3: fp32 {W_hh0, W_hh1, W_ih1} -> bf16 MFMA B-fragment order.
//   gemm_xp: xp0 = x @ W_ih0^T (bf16 MFMA).
//   lstm_pipe3 (R11): chunk-pipelined acquisition. 96 wgs, 3 roles of 32.
//   Per step, the 512-col h snapshot is consumed as 16 independent 32-col
//   k-chunks: wave v stages chunks {v,4+v,8+v,12+v} (global pair poll ->
//   LDS write -> release LDS flag), all waves consume chunks 0..15 in order
//   behind per-chunk LDS acquire flags, MFMA-ing each chunk as it lands.
//   Cross-wg latency is overlapped with the MFMA pipeline instead of being
//   serialized in front of it.
//     role0 L0 : self-recurrence via hbuf0 pairs (depth-4), hs0 -> hring
//                (depth-16 pairs). Fire-and-forget; fX[.][t-16] backpressure.
//     role1 XP1: chunk-consumes hring (always ready; L0 runs ahead), stores
//                xp1r slot + vmcnt + fX flag (proven edge). fL1[t-4] BP.
//     role2 L1 : fX prefetched 1 step ahead (flag-THEN-data order kept),
//                xpr loads at step top (off-path), chunked self-poll hbuf1.
// ---------------------------------------------------------------------------

typedef __bf16 bf16x8 __attribute__((ext_vector_type(8)));
typedef float  f32x4  __attribute__((ext_vector_type(4)));
typedef float  f32x2  __attribute__((ext_vector_type(2)));
typedef unsigned long long u64;
typedef unsigned int u32;

#define MFMA16(a, b, c) __builtin_amdgcn_mfma_f32_16x16x32_bf16((a), (b), (c), 0, 0, 0)
#define SCOPE_AGENT __HIP_MEMORY_SCOPE_AGENT
#define SCOPE_WG    __HIP_MEMORY_SCOPE_WORKGROUP
#define AL64(p) __hip_atomic_load((p), __ATOMIC_RELAXED, SCOPE_AGENT)
#define AL32(p) __hip_atomic_load((p), __ATOMIC_RELAXED, SCOPE_AGENT)
#define AS64(p, v) __hip_atomic_store((p), (v), __ATOMIC_RELAXED, SCOPE_AGENT)
#define AS32(p, v) __hip_atomic_store((p), (v), __ATOMIC_RELAXED, SCOPE_AGENT)

__device__ __forceinline__ float fsigm(float x) { return 1.0f / (1.0f + __expf(-x)); }
__device__ __forceinline__ float ftanh(float x) {
    x = fminf(15.0f, fmaxf(-15.0f, x));
    float e = __expf(2.0f * x);
    return (e - 1.0f) / (e + 1.0f);
}

__device__ __forceinline__ bf16x8 frag_from(u64 lo, u64 hi) {
    union { u64 u[2]; bf16x8 v; } x;
    x.u[0] = lo; x.u[1] = hi;
    return x.v;
}

// ---------------------------------------------------------------------------
// Chunk-pipelined acquire + GEMM of one 32x512 bf16 snapshot stored as
// {bf16x2 data, u32 phase} u64 pairs. Wave v stages chunks {4c+v}; all waves
// consume chunks 0..15 behind per-chunk LDS flags (phase lph, monotone).
// Deadlock-free: staging is flag-unconditional; flags only ever advance.
// ---------------------------------------------------------------------------
__device__ __forceinline__ void chunk_gemm(const u64* __restrict__ src, u32 ph,
                                           u32 lph, const bf16x8 (&wreg)[16],
                                           __bf16* lds_h, u32* chready, int tid,
                                           f32x4& acc0, f32x4& acc1) {
    const int lane = tid & 63, v = tid >> 6;
    const int row = lane & 31, grp = lane >> 5;          // staging mapping
    const int arow = lane & 15, kq8 = (lane >> 4) * 8;   // consume mapping
    const int pbase = row * 256 + grp * 8;
    u64 q[4][8];

    // issue chunk v (c=0) loads
#pragma unroll
    for (int j = 0; j < 8; j++) q[0][j] = AL64(src + pbase + v * 16 + j);

#pragma unroll
    for (int c = 0; c < 4; c++) {
        const int kks = 4 * c + v;
        if (c < 3) {  // issue next own chunk (2-deep pipeline)
#pragma unroll
            for (int j = 0; j < 8; j++)
                q[c + 1][j] = AL64(src + pbase + (4 * (c + 1) + v) * 16 + j);
        }
        // validate own chunk (selective retry)
        for (;;) {
            u32 bad = 0;
#pragma unroll
            for (int j = 0; j < 8; j++) bad |= (u32)(q[c][j] >> 32) ^ ph;
            if (bad == 0) break;
#pragma unroll
            for (int j = 0; j < 8; j++)
                if ((u32)(q[c][j] >> 32) != ph)
                    q[c][j] = AL64(src + pbase + kks * 16 + j);
        }
        // write own chunk into LDS (strip phases), release flag
        {
            __bf16* wp = lds_h + row * 516 + kks * 32 + grp * 16;
#pragma unroll
            for (int j2 = 0; j2 < 4; j2++) {
                u64 val = (q[c][2 * j2] & 0xFFFFFFFFull) | (q[c][2 * j2 + 1] << 32);
                *(u64*)(wp + 4 * j2) = val;
            }
        }
        __hip_atomic_store(&chready[kks], lph, __ATOMIC_RELEASE, SCOPE_WG);

        // consume chunks 4c .. 4c+3 behind LDS acquire flags
#pragma unroll
        for (int k2 = 0; k2 < 4; k2++) {
            const int kk = 4 * c + k2;
            while (__hip_atomic_load(&chready[kk], __ATOMIC_ACQUIRE, SCOPE_WG) != lph) {}
            const __bf16* p0 = lds_h + arow * 516 + kk * 32 + kq8;
            const __bf16* p1 = p0 + 16 * 516;
            bf16x8 a0 = frag_from(*(const u64*)p0, *(const u64*)(p0 + 4));
            bf16x8 a1 = frag_from(*(const u64*)p1, *(const u64*)(p1 + 4));
            acc0 = MFMA16(a0, wreg[kk], acc0);
            acc1 = MFMA16(a1, wreg[kk], acc1);
        }
    }
}

// ---------------------------------------------------------------------------
// Pack [2048][512] fp32 -> per-(wg,wave,ktile) bf16 B-fragment order.
// ---------------------------------------------------------------------------
__global__ void pack_w3(const float* __restrict__ W0, const float* __restrict__ W1,
                        const float* __restrict__ W2, __bf16* __restrict__ O0,
                        __bf16* __restrict__ O1, __bf16* __restrict__ O2) {
    int gtid = blockIdx.x * 256 + threadIdx.x;          // 0 .. 393215
    int sel  = gtid >> 17;                              // 0,1,2
    const float* W = (sel == 0) ? W0 : (sel == 1) ? W1 : W2;
    __bf16* WB     = (sel == 0) ? O0 : (sel == 1) ? O1 : O2;
    int tid  = gtid & 131071;
    int lane = tid & 63;
    int kk   = (tid >> 6) & 15;
    int v    = (tid >> 10) & 3;
    int w    = tid >> 12;                               // 0..31
    int n    = v * 16 + (lane & 15);
    int grow = (n >> 4) * 512 + w * 16 + (n & 15);
    int k0   = kk * 32 + (lane >> 4) * 8;
    const float* src = W + (size_t)grow * 512 + k0;
    bf16x8 val;
#pragma unroll
    for (int e = 0; e < 8; e++) val[e] = (__bf16)src[e];
    *(bf16x8*)(WB + (size_t)tid * 8) = val;
}

// ---------------------------------------------------------------------------
// xp0[r][n] = sum_k x_perm(r)[k] * W[n][k], r = t*32+b, x is [B,T,D] fp32.
// ---------------------------------------------------------------------------
__global__ __launch_bounds__(256, 2) void gemm_xp(const float* __restrict__ A,
                                                  const float* __restrict__ W,
                                                  __bf16* __restrict__ out, int K) {
    const int tid = threadIdx.x, lane = tid & 63, wv = tid >> 6;
    const int bm = blockIdx.x >> 4, bn = blockIdx.x & 15;
    const int m_base = bm * 128 + (wv & 1) * 64;
    const int n_base = bn * 128 + (wv >> 1) * 64;
    const int kq = (lane >> 4) * 8;
    const int rl = lane & 15;

    f32x4 acc[4][4];
#pragma unroll
    for (int i = 0; i < 4; i++)
#pragma unroll
        for (int j = 0; j < 4; j++) acc[i][j] = (f32x4){0.f, 0.f, 0.f, 0.f};

    const int nk = K >> 5;
    for (int kk = 0; kk < nk; kk++) {
        int k0 = kk * 32 + kq;
        bf16x8 af[4], bfr[4];
#pragma unroll
        for (int mt = 0; mt < 4; mt++) {
            int row = m_base + mt * 16 + rl;
            const float* ap = A + (size_t)((row & 31) * 1024 + (row >> 5)) * K + k0;
#pragma unroll
            for (int e = 0; e < 8; e++) af[mt][e] = (__bf16)ap[e];
        }
#pragma unroll
        for (int nt = 0; nt < 4; nt++) {
            int n = n_base + nt * 16 + rl;
            const float* wp = W + (size_t)n * K + k0;
#pragma unroll
            for (int e = 0; e < 8; e++) bfr[nt][e] = (__bf16)wp[e];
        }
#pragma unroll
        for (int mt = 0; mt < 4; mt++)
#pragma unroll
            for (int nt = 0; nt < 4; nt++)
                acc[mt][nt] = MFMA16(af[mt], bfr[nt], acc[mt][nt]);
    }

    const int rq = (lane >> 4) * 4;
#pragma unroll
    for (int mt = 0; mt < 4; mt++)
#pragma unroll
        for (int nt = 0; nt < 4; nt++)
#pragma unroll
            for (int r = 0; r < 4; r++) {
                int row = m_base + mt * 16 + rq + r;
                int col = n_base + nt * 16 + rl;
                out[(size_t)row * 2048 + col] = (__bf16)acc[mt][nt][r];
            }
}

// ---------------------------------------------------------------------------
// 3-stage pipelined recurrence. 96 wgs x 256. role = blockIdx/32, w = %32.
// Static LDS: 33.0 KB staging + 8.7 KB gates + 64 B flags.
// ---------------------------------------------------------------------------
__global__ __launch_bounds__(256, 1) void lstm_pipe3(
    const __bf16* __restrict__ xp0,    // [32768][2048] bf16, row = t*32+b
    const __bf16* __restrict__ WB0,    // W_hh0 packed
    const __bf16* __restrict__ WBw1,   // W_hh1 packed
    const __bf16* __restrict__ WBi1,   // W_ih1 packed
    const float* __restrict__ bias0,
    const float* __restrict__ bias1,
    u64* __restrict__ hbuf0,           // [4][8192] {data,phase} pairs, zeroed
    u64* __restrict__ hbuf1,           // [4][8192] pairs, zeroed
    u64* __restrict__ hring,           // [16][8192] hs0 pairs, zeroed
    __bf16* __restrict__ xp1r,         // [4][32][2048] ring
    float* __restrict__ out_f32,       // [32][1024][512]
    float* __restrict__ hn_out,        // [2][32][512]
    float* __restrict__ cn_out,        // [2][32][512]
    int* __restrict__ fX,              // [32][1024] zeroed (XP1->L1 + L0 BP)
    int* __restrict__ fL1) {           // [32][1024] zeroed (L1->XP1 BP)
    const int tid  = threadIdx.x;
    const int role = blockIdx.x >> 5;   // 0=L0, 1=XP1, 2=L1
    const int w    = blockIdx.x & 31;
    const int lane = tid & 63;
    const int wv   = tid >> 6;

    __shared__ __bf16 lds_h[32 * 516];  // chunked snapshot (stride 516)
    __shared__ float  g_lds[32 * 68];   // gates [32 b][64 cols +4]
    __shared__ u32    chready[16];      // per-chunk phase flags

    if (tid < 16) chready[tid] = 0;
    __syncthreads();

    // --- weights resident in registers (64 VGPRs/lane) ---
    bf16x8 wreg[16];
    {
        const __bf16* WB = (role == 0) ? WB0 : (role == 1) ? WBi1 : WBw1;
        const __bf16* wb = WB + (size_t)(w * 4 + wv) * 16 * 512 + lane * 8;
#pragma unroll
        for (int kk = 0; kk < 16; kk++) wreg[kk] = *(const bf16x8*)(wb + kk * 512);
    }

    // --- elementwise mapping: thread -> (b, j0, j0+1) ---
    const int b  = tid >> 3;
    const int jp = tid & 7;
    const int j0 = w * 16 + jp * 2;
    const int pi = b * 256 + w * 8 + jp;   // pair index in snapshots

    f32x2 bsv[4];
    if (role != 1) {
        const float* bias = (role == 0) ? bias0 : bias1;
#pragma unroll
        for (int g = 0; g < 4; g++) bsv[g] = *(const f32x2*)(bias + g * 512 + j0);
    }
    float cc0 = 0.f, cc1 = 0.f;

    if (role == 0) {
        // =================== L0: layer-0 recurrence ===================
        u32 xc[4], xn[4];
#pragma unroll
        for (int g = 0; g < 4; g++)
            xc[g] = *(const u32*)(xp0 + (size_t)b * 2048 + g * 512 + j0);

        for (int t = 0; t < 1024; t++) {
            // ring backpressure pre-load (write-once addr, off critical path)
            u32 bpv = 1;
            if (tid < 32 && t >= 16) bpv = (u32)AL32(&fX[tid * 1024 + t - 16]);

            f32x4 acc0 = (f32x4){0.f, 0.f, 0.f, 0.f};
            f32x4 acc1 = (f32x4){0.f, 0.f, 0.f, 0.f};
            if (t > 0)
                chunk_gemm(hbuf0 + (size_t)(t & 3) * 8192, (u32)(t >> 2) + 1,
                           (u32)(t + 1), wreg, lds_h, chready, tid, acc0, acc1);

            // backpressure finalize BEFORE the step barrier (gates the stores)
            if (tid < 32 && t >= 16)
                while (bpv == 0) bpv = (u32)AL32(&fX[tid * 1024 + t - 16]);
            asm volatile("" ::: "memory");

            // xp0 prefetch for t+1 (lands during gates)
            {
                int tn = (t < 1023) ? t + 1 : 1023;
#pragma unroll
                for (int g = 0; g < 4; g++)
                    xn[g] = *(const u32*)(xp0 + (size_t)(tn * 32 + b) * 2048 + g * 512 + j0);
            }

            // gates staging
            {
                int col   = wv * 16 + (lane & 15);
                int rbase = (lane >> 4) * 4;
#pragma unroll
                for (int r = 0; r < 4; r++) {
                    g_lds[(rbase + r) * 68 + col]      = acc0[r];
                    g_lds[(16 + rbase + r) * 68 + col] = acc1[r];
                }
            }
            __syncthreads();
            const float* gl = g_lds + b * 68 + jp * 2;
            f32x2 gi = *(const f32x2*)(gl);
            f32x2 gf = *(const f32x2*)(gl + 16);
            f32x2 gg = *(const f32x2*)(gl + 32);
            f32x2 go = *(const f32x2*)(gl + 48);
            __syncthreads();   // g_lds values captured; next step may overwrite

            float hf0, hf1;
            {
                union { u32 u; __bf16 v2[2]; } xi, xf, xg, xo;
                xi.u = xc[0]; xf.u = xc[1]; xg.u = xc[2]; xo.u = xc[3];
                float i0 = fsigm(gi[0] + (float)xi.v2[0] + bsv[0][0]);
                float f0 = fsigm(gf[0] + (float)xf.v2[0] + bsv[1][0]);
                float g0 = ftanh(gg[0] + (float)xg.v2[0] + bsv[2][0]);
                float o0 = fsigm(go[0] + (float)xo.v2[0] + bsv[3][0]);
                cc0 = f0 * cc0 + i0 * g0;
                hf0 = o0 * ftanh(cc0);
                float i1 = fsigm(gi[1] + (float)xi.v2[1] + bsv[0][1]);
                float f1 = fsigm(gf[1] + (float)xf.v2[1] + bsv[1][1]);
                float g1 = ftanh(gg[1] + (float)xg.v2[1] + bsv[2][1]);
                float o1 = fsigm(go[1] + (float)xo.v2[1] + bsv[3][1]);
                cc1 = f1 * cc1 + i1 * g1;
                hf1 = o1 * ftanh(cc1);
            }
            union { __bf16 v2[2]; u32 u; } hu;
            hu.v2[0] = (__bf16)hf0; hu.v2[1] = (__bf16)hf1;

            // fire-and-forget: self pair (depth-4) + hs0 ring pair (depth-16)
            u64 hp_rec = (u64)hu.u | ((u64)((u32)((t + 1) >> 2) + 1) << 32);
            AS64(hbuf0 + (size_t)((t + 1) & 3) * 8192 + pi, hp_rec);
            u64 hp_ring = (u64)hu.u | ((u64)(u32)(t + 1) << 32);
            AS64(hring + (size_t)(t & 15) * 8192 + pi, hp_ring);

            if (t == 1023) {
                *(f32x2*)(hn_out + (size_t)b * 512 + j0) = (f32x2){hf0, hf1};
                *(f32x2*)(cn_out + (size_t)b * 512 + j0) = (f32x2){cc0, cc1};
            }
#pragma unroll
            for (int g = 0; g < 4; g++) xc[g] = xn[g];
        }
    } else if (role == 1) {
        // =================== XP1: xp1(t) = hs0(t) @ W_ih1^T ===================
        for (int t = 0; t < 1024; t++) {
            // xp1r slot backpressure: speculative load, resolve before stores
            u32 blv = 1;
            if (t >= 4) blv = (u32)AL32(&fL1[w * 1024 + t - 4]);

            f32x4 acc0 = (f32x4){0.f, 0.f, 0.f, 0.f};
            f32x4 acc1 = (f32x4){0.f, 0.f, 0.f, 0.f};
            chunk_gemm(hring + (size_t)(t & 15) * 8192, (u32)(t + 1),
                       (u32)(t + 1), wreg, lds_h, chready, tid, acc0, acc1);

            {
                int col   = wv * 16 + (lane & 15);
                int rbase = (lane >> 4) * 4;
#pragma unroll
                for (int r = 0; r < 4; r++) {
                    g_lds[(rbase + r) * 68 + col]      = acc0[r];
                    g_lds[(16 + rbase + r) * 68 + col] = acc1[r];
                }
            }
            __syncthreads();
            const float* gl = g_lds + b * 68 + jp * 2;
            f32x2 gv0 = *(const f32x2*)(gl);
            f32x2 gv1 = *(const f32x2*)(gl + 16);
            f32x2 gv2 = *(const f32x2*)(gl + 32);
            f32x2 gv3 = *(const f32x2*)(gl + 48);
            __syncthreads();

            if (blv == 0)
                while ((u32)AL32(&fL1[w * 1024 + t - 4]) == 0) {}
            asm volatile("" ::: "memory");

            __bf16* xd = xp1r + (size_t)(t & 3) * 65536 + (size_t)b * 2048 + j0;
            {
                union { __bf16 v2[2]; u32 u; } pu;
                pu.v2[0] = (__bf16)gv0[0]; pu.v2[1] = (__bf16)gv0[1];
                AS32((u32*)(xd), pu.u);
                pu.v2[0] = (__bf16)gv1[0]; pu.v2[1] = (__bf16)gv1[1];
                AS32((u32*)(xd + 512), pu.u);
                pu.v2[0] = (__bf16)gv2[0]; pu.v2[1] = (__bf16)gv2[1];
                AS32((u32*)(xd + 1024), pu.u);
                pu.v2[0] = (__bf16)gv3[0]; pu.v2[1] = (__bf16)gv3[1];
                AS32((u32*)(xd + 1536), pu.u);
            }
            asm volatile("s_waitcnt vmcnt(0)" ::: "memory");
            __syncthreads();
            if (tid == 0) AS32(&fX[w * 1024 + t], 1);
        }
    } else {
        // =================== L1: layer-1 recurrence ===================
        u32 fx_next = (u32)AL32(&fX[w * 1024]);   // prefetched fX[w][0]
        for (int t = 0; t < 1024; t++) {
            // flag-then-data: fx_next was read >=1 step ago; if set, xpr loads
            // issued now are guaranteed to see XP1's stores.
            if (fx_next == 0)
                while ((u32)AL32(&fX[w * 1024 + t]) == 0) {}
            asm volatile("" ::: "memory");
            u32 xpr[4];
            {
                const __bf16* xs = xp1r + (size_t)(t & 3) * 65536 + (size_t)b * 2048 + j0;
#pragma unroll
                for (int g = 0; g < 4; g++)
                    xpr[g] = AL32((const u32*)(xs + g * 512));
            }
            fx_next = (t < 1023) ? (u32)AL32(&fX[w * 1024 + t + 1]) : 1u;

            f32x4 acc0 = (f32x4){0.f, 0.f, 0.f, 0.f};
            f32x4 acc1 = (f32x4){0.f, 0.f, 0.f, 0.f};
            if (t > 0)
                chunk_gemm(hbuf1 + (size_t)(t & 3) * 8192, (u32)(t >> 2) + 1,
                           (u32)(t + 1), wreg, lds_h, chready, tid, acc0, acc1);

            {
                int col   = wv * 16 + (lane & 15);
                int rbase = (lane >> 4) * 4;
#pragma unroll
                for (int r = 0; r < 4; r++) {
                    g_lds[(rbase + r) * 68 + col]      = acc0[r];
                    g_lds[(16 + rbase + r) * 68 + col] = acc1[r];
                }
            }
            __syncthreads();
            const float* gl = g_lds + b * 68 + jp * 2;
            f32x2 gi = *(const f32x2*)(gl);
            f32x2 gf = *(const f32x2*)(gl + 16);
            f32x2 gg = *(const f32x2*)(gl + 32);
            f32x2 go = *(const f32x2*)(gl + 48);
            __syncthreads();

            float hf0, hf1;
            {
                union { u32 u; __bf16 v2[2]; } xi, xf, xg, xo;
                xi.u = xpr[0]; xf.u = xpr[1]; xg.u = xpr[2]; xo.u = xpr[3];
                float i0 = fsigm(gi[0] + (float)xi.v2[0] + bsv[0][0]);
                float f0 = fsigm(gf[0] + (float)xf.v2[0] + bsv[1][0]);
                float g0 = ftanh(gg[0] + (float)xg.v2[0] + bsv[2][0]);
                float o0 = fsigm(go[0] + (float)xo.v2[0] + bsv[3][0]);
                cc0 = f0 * cc0 + i0 * g0;
                hf0 = o0 * ftanh(cc0);
                float i1 = fsigm(gi[1] + (float)xi.v2[1] + bsv[0][1]);
                float f1 = fsigm(gf[1] + (float)xf.v2[1] + bsv[1][1]);
                float g1 = ftanh(gg[1] + (float)xg.v2[1] + bsv[2][1]);
                float o1 = fsigm(go[1] + (float)xo.v2[1] + bsv[3][1]);
                cc1 = f1 * cc1 + i1 * g1;
                hf1 = o1 * ftanh(cc1);
            }
            union { __bf16 v2[2]; u32 u; } hu;
            hu.v2[0] = (__bf16)hf0; hu.v2[1] = (__bf16)hf1;

            u64 hp_rec = (u64)hu.u | ((u64)((u32)((t + 1) >> 2) + 1) << 32);
            AS64(hbuf1 + (size_t)((t + 1) & 3) * 8192 + pi, hp_rec);
            *(f32x2*)(out_f32 + (size_t)b * 524288 + (size_t)t * 512 + j0) =
                (f32x2){hf0, hf1};
            if (t == 1023) {
                *(f32x2*)(hn_out + 16384 + (size_t)b * 512 + j0) = (f32x2){hf0, hf1};
                *(f32x2*)(cn_out + 16384 + (size_t)b * 512 + j0) = (f32x2){cc0, cc1};
            }
            if (tid == 0) AS32(&fL1[w * 1024 + t], 1);
        }
    }
}

// ---------------------------------------------------------------------------
extern "C" void kernel_launch(void* const* d_in, const int* in_sizes, int n_in,
                              void* d_out, int out_size, void* d_ws, size_t ws_size,
                              hipStream_t stream) {
    (void)in_sizes; (void)n_in; (void)out_size; (void)ws_size;
    const float* x    = (const float*)d_in[0];  // [32][1024][256] fp32
    const float* Wih0 = (const float*)d_in[1];  // [2048][256] fp32
    const float* b0   = (const float*)d_in[2];  // [2048] fp32
    const float* Whh0 = (const float*)d_in[3];  // [2048][512] fp32
    const float* Wih1 = (const float*)d_in[4];  // [2048][512] fp32
    const float* b1   = (const float*)d_in[5];  // [2048] fp32
    const float* Whh1 = (const float*)d_in[6];  // [2048][512] fp32
    float* dout = (float*)d_out;  // fp32: out(16777216) | h_n(2*16384) | c_n(2*16384)

    char* wsb = (char*)d_ws;
    int*    fX    = (int*)wsb;                                  // 128 KB
    int*    fL1   = (int*)(wsb + (128 << 10));                  // 128 KB
    u64*    hbuf0 = (u64*)(wsb + (256 << 10));                  // 256 KB (depth 4)
    u64*    hbuf1 = (u64*)(wsb + (512 << 10));                  // 256 KB (depth 4)
    u64*    hring = (u64*)(wsb + (768 << 10));                  // 1 MB (depth 16)
    __bf16* xp1r  = (__bf16*)(wsb + (1792 << 10));              // 512 KB
    __bf16* WB0   = (__bf16*)(wsb + (2304 << 10));              // 2 MB
    __bf16* WBw1  = (__bf16*)(wsb + (2304 << 10) + (2 << 20));  // 2 MB
    __bf16* WBi1  = (__bf16*)(wsb + (2304 << 10) + (4 << 20));  // 2 MB
    __bf16* xpb   = (__bf16*)(wsb + (16 << 20));                // 128 MB

    // zero flags + pair buffers + hs0 ring (contiguous 1792 KB)
    (void)hipMemsetAsync(wsb, 0, 1792 << 10, stream);

    pack_w3<<<dim3(1536), dim3(256), 0, stream>>>(Whh0, Whh1, Wih1, WB0, WBw1, WBi1);

    // xp0 = x @ Wih0^T  (K=256, fp32 A, permuted rows)
    gemm_xp<<<dim3(4096), dim3(256), 0, stream>>>(x, Wih0, xpb, 256);

    lstm_pipe3<<<dim3(96), dim3(256), 0, stream>>>(
        xpb, WB0, WBw1, WBi1, b0, b1, hbuf0, hbuf1, hring, xp1r,
        dout, dout + 16777216, dout + 16777216 + 32768, fX, fL1);
}

// Round 6
// 3872.639 us; speedup vs baseline: 2.0951x; 2.0951x over previous
//
#include <hip/hip_runtime.h>

// ---------------------------------------------------------------------------
// 2-layer LSTM, T=1024, B=32, D=256, H=512. Inputs fp32, OUTPUT fp32.
//   pack_w3: fp32 {W_hh0, W_hh1, W_ih1} -> bf16 MFMA B-fragment order.
//   gemm_xp: xp0 = x @ W_ih0^T (bf16 MFMA).
//   lstm_pipe3: persistent 96-wg x 256-thr kernel, 3 stages of 32 wgs:
//     role0 L0 : layer0 recurrence (R6-shape loop, fan-in-32 flag barrier),
//                writes hs0[t] slots (write-once) + own double buffer.
//     role1 XP1: stateless xp1[t] = hs0[t] @ Wih1^T. NO self-sync (batch rows
//                independent). Ring depth 4, backpressure on L1[t-4].
//     role2 L1 : layer1 recurrence, loop identical to L0 (32 MFMAs, one
//                staging) + fan-in-1 poll of its matching XP1 wg + 4 direct
//                xp word loads (no LDS staging for xp1).
//   All exchange via proven fence-free relaxed agent atomics (R5/R6).
//
// R12 NOTE (session verdict): this is the R0 baseline restored verbatim.
// Rounds R7-R11 tested four alternative exchange protocols (pair-poll,
// fused 2-stage fire-and-forget, selective-retry pairs, chunk-pipelined
// acquisition); all regressed (3.7/7.7/4.4/7.9 ms vs 3.53 ms). The ~3.4 us
// step is a MALL-latency structural floor for a fan-in-32 exchange:
// store-visibility + discovery round trip cannot be removed by protocol
// encoding, and intra-CU alternatives fail on weight bandwidth. Counters
// here show latency-bound (HBM ~4.6%, MfmaUtil ~2.3%), not a HW roofline.
// ---------------------------------------------------------------------------

typedef __bf16 bf16x8 __attribute__((ext_vector_type(8)));
typedef float  f32x4  __attribute__((ext_vector_type(4)));
typedef float  f32x2  __attribute__((ext_vector_type(2)));
typedef unsigned long long u64;
typedef unsigned int u32;

#define MFMA16(a, b, c) __builtin_amdgcn_mfma_f32_16x16x32_bf16((a), (b), (c), 0, 0, 0)
#define SCOPE_AGENT __HIP_MEMORY_SCOPE_AGENT

__device__ __forceinline__ float fsigm(float x) { return 1.0f / (1.0f + __expf(-x)); }
__device__ __forceinline__ float ftanh(float x) {
    x = fminf(15.0f, fmaxf(-15.0f, x));
    float e = __expf(2.0f * x);
    return (e - 1.0f) / (e + 1.0f);
}

__device__ __forceinline__ bf16x8 frag_from(u64 lo, u64 hi) {
    union { u64 u[2]; bf16x8 v; } x;
    x.u[0] = lo; x.u[1] = hi;
    return x.v;
}

// ---------------------------------------------------------------------------
// Pack [2048][512] fp32 -> per-(wg,wave,ktile) bf16 B-fragment order:
//   WB[((w*4+v)*16+kk)*512 + lane*8 + e] = bf16(W[grow][k0+e])
//   n = v*16+(lane&15); grow = (n>>4)*512 + w*16 + (n&15); k0 = kk*32+(lane>>4)*8
// wg w owns h-cols [w*16, w*16+16) for all 4 gates.
// ---------------------------------------------------------------------------
__global__ void pack_w3(const float* __restrict__ W0, const float* __restrict__ W1,
                        const float* __restrict__ W2, __bf16* __restrict__ O0,
                        __bf16* __restrict__ O1, __bf16* __restrict__ O2) {
    int gtid = blockIdx.x * 256 + threadIdx.x;          // 0 .. 393215
    int sel  = gtid >> 17;                              // 0,1,2
    const float* W = (sel == 0) ? W0 : (sel == 1) ? W1 : W2;
    __bf16* WB     = (sel == 0) ? O0 : (sel == 1) ? O1 : O2;
    int tid  = gtid & 131071;
    int lane = tid & 63;
    int kk   = (tid >> 6) & 15;
    int v    = (tid >> 10) & 3;
    int w    = tid >> 12;                               // 0..31
    int n    = v * 16 + (lane & 15);
    int grow = (n >> 4) * 512 + w * 16 + (n & 15);
    int k0   = kk * 32 + (lane >> 4) * 8;
    const float* src = W + (size_t)grow * 512 + k0;
    bf16x8 val;
#pragma unroll
    for (int e = 0; e < 8; e++) val[e] = (__bf16)src[e];
    *(bf16x8*)(WB + (size_t)tid * 8) = val;
}

// ---------------------------------------------------------------------------
// xp0[r][n] = sum_k x_perm(r)[k] * W[n][k], r = t*32+b, x is [B,T,D] fp32.
// ---------------------------------------------------------------------------
__global__ __launch_bounds__(256, 2) void gemm_xp(const float* __restrict__ A,
                                                  const float* __restrict__ W,
                                                  __bf16* __restrict__ out, int K) {
    const int tid = threadIdx.x, lane = tid & 63, wv = tid >> 6;
    const int bm = blockIdx.x >> 4, bn = blockIdx.x & 15;
    const int m_base = bm * 128 + (wv & 1) * 64;
    const int n_base = bn * 128 + (wv >> 1) * 64;
    const int kq = (lane >> 4) * 8;
    const int rl = lane & 15;

    f32x4 acc[4][4];
#pragma unroll
    for (int i = 0; i < 4; i++)
#pragma unroll
        for (int j = 0; j < 4; j++) acc[i][j] = (f32x4){0.f, 0.f, 0.f, 0.f};

    const int nk = K >> 5;
    for (int kk = 0; kk < nk; kk++) {
        int k0 = kk * 32 + kq;
        bf16x8 af[4], bfr[4];
#pragma unroll
        for (int mt = 0; mt < 4; mt++) {
            int row = m_base + mt * 16 + rl;
            const float* ap = A + (size_t)((row & 31) * 1024 + (row >> 5)) * K + k0;
#pragma unroll
            for (int e = 0; e < 8; e++) af[mt][e] = (__bf16)ap[e];
        }
#pragma unroll
        for (int nt = 0; nt < 4; nt++) {
            int n = n_base + nt * 16 + rl;
            const float* wp = W + (size_t)n * K + k0;
#pragma unroll
            for (int e = 0; e < 8; e++) bfr[nt][e] = (__bf16)wp[e];
        }
#pragma unroll
        for (int mt = 0; mt < 4; mt++)
#pragma unroll
            for (int nt = 0; nt < 4; nt++)
                acc[mt][nt] = MFMA16(af[mt], bfr[nt], acc[mt][nt]);
    }

    const int rq = (lane >> 4) * 4;
#pragma unroll
    for (int mt = 0; mt < 4; mt++)
#pragma unroll
        for (int nt = 0; nt < 4; nt++)
#pragma unroll
            for (int r = 0; r < 4; r++) {
                int row = m_base + mt * 16 + rq + r;
                int col = n_base + nt * 16 + rl;
                out[(size_t)row * 2048 + col] = (__bf16)acc[mt][nt][r];
            }
}

// ---------------------------------------------------------------------------
// 3-stage pipelined recurrence. 96 wgs x 256. role = blockIdx/32, w = %32.
// wg w (any role) owns h-cols [w*16, w*16+16) x 4 gates.
// ---------------------------------------------------------------------------
__global__ __launch_bounds__(256, 1) void lstm_pipe3(
    const __bf16* __restrict__ xp0,    // [32768][2048] bf16, row = t*32+b
    const __bf16* __restrict__ WB0,    // W_hh0 packed
    const __bf16* __restrict__ WBw1,   // W_hh1 packed
    const __bf16* __restrict__ WBi1,   // W_ih1 packed
    const float* __restrict__ bias0,
    const float* __restrict__ bias1,
    __bf16* __restrict__ hbuf0,        // [2][32][512] zeroed
    __bf16* __restrict__ hbuf1,        // [2][32][512] zeroed
    __bf16* __restrict__ hs0s,         // [1024][32][512] write-once slots
    __bf16* __restrict__ xp1r,         // [4][32][2048] ring
    float* __restrict__ out_f32,       // [32][1024][512]
    float* __restrict__ hn_out,        // [2][32][512]
    float* __restrict__ cn_out,        // [2][32][512]
    int* __restrict__ fL0,             // [32][1024] zeroed, stride 1024
    int* __restrict__ fX,              // [32][1024] zeroed
    int* __restrict__ fL1) {           // [32][1024] zeroed
    const int tid  = threadIdx.x;
    const int role = blockIdx.x >> 5;   // 0=L0, 1=XP1, 2=L1
    const int w    = blockIdx.x & 31;
    const int lane = tid & 63;
    const int wv   = tid >> 6;

    __shared__ __bf16 h_lds[32 * 516];  // staged state (stride 516)
    __shared__ float  g_lds[32 * 68];   // gates [32 b][64 cols +4]

    // --- weights resident in registers (64 VGPRs/lane) ---
    bf16x8 wreg[16];
    {
        const __bf16* WB = (role == 0) ? WB0 : (role == 1) ? WBi1 : WBw1;
        const __bf16* wb = WB + (size_t)(w * 4 + wv) * 16 * 512 + lane * 8;
#pragma unroll
        for (int kk = 0; kk < 16; kk++) wreg[kk] = *(const bf16x8*)(wb + kk * 512);
    }

    // --- elementwise mapping: thread -> (b, j0, j0+1) ---
    const int b  = tid >> 3;
    const int jp = tid & 7;
    const int j0 = w * 16 + jp * 2;
    const int arow = lane & 15;
    const int kq8  = (lane >> 4) * 8;

    f32x2 bsv[4];
    if (role != 1) {
        const float* bias = (role == 0) ? bias0 : bias1;
#pragma unroll
        for (int g = 0; g < 4; g++) bsv[g] = *(const f32x2*)(bias + g * 512 + j0);
    }
    float cc0 = 0.f, cc1 = 0.f;

    __bf16* hbuf = (role == 0) ? hbuf0 : hbuf1;   // recurrent double buffer
    int* fMy = (role == 0) ? fL0 : (role == 1) ? fX : fL1;

    // xp0 prefetch (role 0 only)
    u32 xc[4] = {0, 0, 0, 0}, xn[4] = {0, 0, 0, 0};
    if (role == 0) {
#pragma unroll
        for (int g = 0; g < 4; g++)
            xc[g] = *(const u32*)(xp0 + (size_t)b * 2048 + g * 512 + j0);
    }

    for (int t = 0; t < 1024; t++) {
        // ---------------- top-of-step wait ----------------
        if (role == 0) {
            int tn = (t < 1023) ? t + 1 : 1023;
#pragma unroll
            for (int g = 0; g < 4; g++)
                xn[g] = *(const u32*)(xp0 + (size_t)(tn * 32 + b) * 2048 + g * 512 + j0);
            if (t > 0) {
                if (tid < 32)
                    while (__hip_atomic_load(&fL0[tid * 1024 + t - 1], __ATOMIC_RELAXED,
                                             SCOPE_AGENT) == 0) {}
                asm volatile("" ::: "memory");
                __syncthreads();
            }
        } else if (role == 1) {
            if (tid < 32)
                while (__hip_atomic_load(&fL0[tid * 1024 + t], __ATOMIC_RELAXED,
                                         SCOPE_AGENT) == 0) {}
            else if (tid == 32 && t >= 4)
                while (__hip_atomic_load(&fL1[w * 1024 + t - 4], __ATOMIC_RELAXED,
                                         SCOPE_AGENT) == 0) {}
            asm volatile("" ::: "memory");
            __syncthreads();
        } else {
            if (tid < 32) {
                if (t > 0)
                    while (__hip_atomic_load(&fL1[tid * 1024 + t - 1], __ATOMIC_RELAXED,
                                             SCOPE_AGENT) == 0) {}
            } else if (tid == 32) {
                while (__hip_atomic_load(&fX[w * 1024 + t], __ATOMIC_RELAXED,
                                         SCOPE_AGENT) == 0) {}
            }
            asm volatile("" ::: "memory");
            __syncthreads();
        }

        // ---------------- stage state into LDS ----------------
        // role0: hbuf0[t&1]; role1: hs0s[t]; role2: xp words + hbuf1[t&1]
        u32 xpr[4];
        if (role == 2) {
            const __bf16* xs = xp1r + (size_t)(t & 3) * 65536 + (size_t)b * 2048 + j0;
#pragma unroll
            for (int g = 0; g < 4; g++)
                xpr[g] = __hip_atomic_load((const u32*)(xs + g * 512),
                                           __ATOMIC_RELAXED, SCOPE_AGENT);
        }
        {
            const u64* hg = (role == 1)
                ? (const u64*)(hs0s + (size_t)t * 16384)
                : (const u64*)(hbuf + (size_t)(t & 1) * 16384);
            u64 hv[16];
#pragma unroll
            for (int i = 0; i < 16; i++)
                hv[i] = __hip_atomic_load(hg + i * 256 + tid, __ATOMIC_RELAXED, SCOPE_AGENT);
#pragma unroll
            for (int i = 0; i < 16; i++) {
                int f  = (i * 256 + tid) * 4;
                int br = f >> 9, col = f & 511;
                *(u64*)(h_lds + br * 516 + col) = hv[i];
            }
        }
        __syncthreads();

        // ---------------- 32 MFMAs ----------------
        f32x4 acc0 = (f32x4){0.f, 0.f, 0.f, 0.f};
        f32x4 acc1 = (f32x4){0.f, 0.f, 0.f, 0.f};
#pragma unroll
        for (int kk = 0; kk < 16; kk++) {
            const __bf16* p0 = h_lds + arow * 516 + kq8 + kk * 32;
            const __bf16* p1 = p0 + 16 * 516;
            bf16x8 a0 = frag_from(*(const u64*)p0, *(const u64*)(p0 + 4));
            bf16x8 a1 = frag_from(*(const u64*)p1, *(const u64*)(p1 + 4));
            acc0 = MFMA16(a0, wreg[kk], acc0);
            acc1 = MFMA16(a1, wreg[kk], acc1);
        }
        {
            int col   = wv * 16 + (lane & 15);
            int rbase = (lane >> 4) * 4;
#pragma unroll
            for (int r = 0; r < 4; r++) {
                g_lds[(rbase + r) * 68 + col]      = acc0[r];
                g_lds[(16 + rbase + r) * 68 + col] = acc1[r];
            }
        }
        __syncthreads();

        // ---------------- per-role epilogue ----------------
        if (role == 1) {
            // pack projection to bf16, store to ring, flag
            const float* gl = g_lds + b * 68 + jp * 2;
            __bf16* xd = xp1r + (size_t)(t & 3) * 65536 + (size_t)b * 2048 + j0;
#pragma unroll
            for (int g = 0; g < 4; g++) {
                f32x2 gv = *(const f32x2*)(gl + g * 16);
                union { __bf16 v2[2]; u32 u; } pu;
                pu.v2[0] = (__bf16)gv[0]; pu.v2[1] = (__bf16)gv[1];
                __hip_atomic_store((u32*)(xd + g * 512), pu.u,
                                   __ATOMIC_RELAXED, SCOPE_AGENT);
            }
            asm volatile("s_waitcnt vmcnt(0)" ::: "memory");
            __syncthreads();
            if (tid == 0)
                __hip_atomic_store(&fX[w * 1024 + t], 1, __ATOMIC_RELAXED, SCOPE_AGENT);
        } else {
            float hf0, hf1;
            {
                u32 x0 = (role == 0) ? xc[0] : xpr[0];
                u32 x1 = (role == 0) ? xc[1] : xpr[1];
                u32 x2 = (role == 0) ? xc[2] : xpr[2];
                u32 x3 = (role == 0) ? xc[3] : xpr[3];
                union { u32 u; __bf16 v2[2]; } xi, xf, xg, xo;
                xi.u = x0; xf.u = x1; xg.u = x2; xo.u = x3;
                const float* gl = g_lds + b * 68 + jp * 2;
                f32x2 gi = *(const f32x2*)(gl);
                f32x2 gf = *(const f32x2*)(gl + 16);
                f32x2 gg = *(const f32x2*)(gl + 32);
                f32x2 go = *(const f32x2*)(gl + 48);

                float i0 = fsigm(gi[0] + (float)xi.v2[0] + bsv[0][0]);
                float f0 = fsigm(gf[0] + (float)xf.v2[0] + bsv[1][0]);
                float g0 = ftanh(gg[0] + (float)xg.v2[0] + bsv[2][0]);
                float o0 = fsigm(go[0] + (float)xo.v2[0] + bsv[3][0]);
                cc0 = f0 * cc0 + i0 * g0;
                hf0 = o0 * ftanh(cc0);

                float i1 = fsigm(gi[1] + (float)xi.v2[1] + bsv[0][1]);
                float f1 = fsigm(gf[1] + (float)xf.v2[1] + bsv[1][1]);
                float g1 = ftanh(gg[1] + (float)xg.v2[1] + bsv[2][1]);
                float o1 = fsigm(go[1] + (float)xo.v2[1] + bsv[3][1]);
                cc1 = f1 * cc1 + i1 * g1;
                hf1 = o1 * ftanh(cc1);
            }
            union { __bf16 v2[2]; u32 u; } hu;
            hu.v2[0] = (__bf16)hf0; hu.v2[1] = (__bf16)hf1;

            // recurrent state store (+ hs0 slot for role 0)
            __hip_atomic_store((u32*)(hbuf + (size_t)((t + 1) & 1) * 16384 +
                                      (size_t)b * 512 + j0),
                               hu.u, __ATOMIC_RELAXED, SCOPE_AGENT);
            if (role == 0)
                __hip_atomic_store((u32*)(hs0s + ((size_t)t * 32 + b) * 512 + j0), hu.u,
                                   __ATOMIC_RELAXED, SCOPE_AGENT);
            asm volatile("s_waitcnt vmcnt(0)" ::: "memory");
            __syncthreads();
            if (tid == 0)
                __hip_atomic_store(&fMy[w * 1024 + t], 1, __ATOMIC_RELAXED, SCOPE_AGENT);

            // non-critical stores overlap flag propagation
            if (role == 2)
                *(f32x2*)(out_f32 + (size_t)b * 524288 + (size_t)t * 512 + j0) =
                    (f32x2){hf0, hf1};
            if (t == 1023) {
                int li = (role == 0) ? 0 : 1;
                *(f32x2*)(hn_out + (size_t)li * 16384 + (size_t)b * 512 + j0) =
                    (f32x2){hf0, hf1};
                *(f32x2*)(cn_out + (size_t)li * 16384 + (size_t)b * 512 + j0) =
                    (f32x2){cc0, cc1};
            }
#pragma unroll
            for (int g = 0; g < 4; g++) xc[g] = xn[g];
        }
    }
}

// ---------------------------------------------------------------------------
extern "C" void kernel_launch(void* const* d_in, const int* in_sizes, int n_in,
                              void* d_out, int out_size, void* d_ws, size_t ws_size,
                              hipStream_t stream) {
    (void)in_sizes; (void)n_in; (void)out_size; (void)ws_size;
    const float* x    = (const float*)d_in[0];  // [32][1024][256] fp32
    const float* Wih0 = (const float*)d_in[1];  // [2048][256] fp32
    const float* b0   = (const float*)d_in[2];  // [2048] fp32
    const float* Whh0 = (const float*)d_in[3];  // [2048][512] fp32
    const float* Wih1 = (const float*)d_in[4];  // [2048][512] fp32
    const float* b1   = (const float*)d_in[5];  // [2048] fp32
    const float* Whh1 = (const float*)d_in[6];  // [2048][512] fp32
    float* dout = (float*)d_out;  // fp32: out(16777216) | h_n(2*16384) | c_n(2*16384)

    char* wsb = (char*)d_ws;
    int*    fL0   = (int*)wsb;                                  // 128 KB
    int*    fX    = (int*)(wsb + (128 << 10));                  // 128 KB
    int*    fL1   = (int*)(wsb + (256 << 10));                  // 128 KB
    __bf16* hbuf0 = (__bf16*)(wsb + (384 << 10));               // 64 KB
    __bf16* hbuf1 = (__bf16*)(wsb + (448 << 10));               // 64 KB
    __bf16* WB0   = (__bf16*)(wsb + (512 << 10));               // 2 MB
    __bf16* WBw1  = (__bf16*)(wsb + (512 << 10) + (2 << 20));   // 2 MB
    __bf16* WBi1  = (__bf16*)(wsb + (512 << 10) + (4 << 20));   // 2 MB
    __bf16* xp1r  = (__bf16*)(wsb + (512 << 10) + (6 << 20));   // 512 KB
    __bf16* hs0s  = (__bf16*)(wsb + (1 << 20) + (7 << 20));     // 32 MB
    __bf16* xpb   = (__bf16*)(wsb + (40 << 20));                // 128 MB

    // zero flags + both h double-buffers (contiguous 512 KB)
    (void)hipMemsetAsync(wsb, 0, 512 << 10, stream);

    pack_w3<<<dim3(1536), dim3(256), 0, stream>>>(Whh0, Whh1, Wih1, WB0, WBw1, WBi1);

    // xp0 = x @ Wih0^T  (K=256, fp32 A, permuted rows)
    gemm_xp<<<dim3(4096), dim3(256), 0, stream>>>(x, Wih0, xpb, 256);

    lstm_pipe3<<<dim3(96), dim3(256), 0, stream>>>(
        xpb, WB0, WBw1, WBi1, b0, b1, hbuf0, hbuf1, hs0s, xp1r,
        dout, dout + 16777216, dout + 16777216 + 32768, fL0, fX, fL1);
}